// Round 1
// baseline (139.684 us; speedup 1.0000x reference)
//
#include <hip/hip_runtime.h>

#define TT 4096
#define DD 64
#define HH 12
#define NTILE 10   // covers [q0-256, q0+64) in 32-key tiles

typedef __attribute__((ext_vector_type(8))) short s8v;
typedef __attribute__((ext_vector_type(4))) short s4v;
typedef __attribute__((ext_vector_type(4))) float f4v;

static __device__ __forceinline__ short f2bf(float f) {
  unsigned u = __builtin_bit_cast(unsigned, f);
  u += 0x7FFFu + ((u >> 16) & 1u);   // RNE
  return (short)(u >> 16);
}

static __device__ __forceinline__ s8v pack8(float4 a, float4 b) {
  s8v r;
  r[0] = f2bf(a.x); r[1] = f2bf(a.y); r[2] = f2bf(a.z); r[3] = f2bf(a.w);
  r[4] = f2bf(b.x); r[5] = f2bf(b.y); r[6] = f2bf(b.z); r[7] = f2bf(b.w);
  return r;
}

static __device__ __forceinline__ f4v MFMA16(s4v a, s4v b, f4v c) {
#if defined(__has_builtin) && __has_builtin(__builtin_amdgcn_mfma_f32_16x16x16bf16_1k)
  return __builtin_amdgcn_mfma_f32_16x16x16bf16_1k(a, b, c, 0, 0, 0);
#else
  asm volatile("v_mfma_f32_16x16x16_bf16 %0, %1, %2, %0\n\ts_nop 7\n\ts_nop 7"
               : "+v"(c) : "v"(a), "v"(b));
  return c;
#endif
}

// Swapped-QK^T flash attention with 256-wide causal window.
// Block: 256 threads = 4 waves; each block: 64 query rows of one (b,h).
// Wave w owns rows qw0..qw0+15 (lane's row = qw0 + (lane&15)).
__global__ __launch_bounds__(256, 4)
void lma_attn_kernel(const float* __restrict__ Q, const float* __restrict__ K,
                     const float* __restrict__ V, const int* __restrict__ laPtr,
                     float* __restrict__ out)
{
  __shared__ short k_lds[32 * 64];   // bf16 K tile [j][d], slot^=(j&7) swizzle
  __shared__ short vt_lds[64 * 32];  // bf16 V^T tile [d][j], slot^=((d>>1)&3)
  __shared__ float o_lds[64][65];    // epilogue transpose

  const int tid = threadIdx.x;
  const int bid = blockIdx.x;
  const int qt = bid & 63;
  const int bh = bid >> 6;
  const int q0 = qt << 6;
  const int la = laPtr[0];           // 256

  const int lane = tid & 63;
  const int w = tid >> 6;
  const int c = lane & 15;           // query column within wave tile
  const int g = lane >> 4;           // lane group
  const int qw0 = q0 + w * 16;
  const int i_row = qw0 + c;
  int jlo = i_row - la + 1; if (jlo < 0) jlo = 0;

  const size_t base = (size_t)bh * (TT * DD);

  // Q fragment (B-operand of S^T = K*Q^T): qf[ch][i] = Q[i_row][32*ch + 8*g + i]
  s8v qf[2];
  {
    const float* qp = Q + base + (size_t)i_row * DD + 8 * g;
    float4 a0 = *(const float4*)(qp);
    float4 a1 = *(const float4*)(qp + 4);
    float4 b0 = *(const float4*)(qp + 32);
    float4 b1 = *(const float4*)(qp + 36);
    qf[0] = pack8(a0, a1);
    qf[1] = pack8(b0, b1);
  }

  f4v acc_o[4] = {{0.f,0.f,0.f,0.f},{0.f,0.f,0.f,0.f},
                  {0.f,0.f,0.f,0.f},{0.f,0.f,0.f,0.f}};  // out^T[d=dt*16+4g+r][q=c]
  float m = -1e30f;
  float lsum = 0.f;

  const int jr = tid >> 3;          // staging row 0..31
  const int d0 = (tid & 7) * 8;     // staging dim start

  for (int t = 0; t < NTILE; ++t) {
    const int kj0 = q0 - 256 + 32 * t;      // tile start; multiple of 32
    if (kj0 < 0) continue;                  // block-uniform

    __syncthreads();
    // ---- stage K (row-major, swizzled) and V^T (transposed, swizzled) ----
    {
      const float* kp = K + base + (size_t)(kj0 + jr) * DD + d0;
      float4 ka = *(const float4*)kp;
      float4 kb = *(const float4*)(kp + 4);
      const int slot = (tid & 7) ^ (jr & 7);
      *(s8v*)&k_lds[jr * 64 + slot * 8] = pack8(ka, kb);

      const float* vp = V + base + (size_t)(kj0 + jr) * DD + d0;
      float4 va = *(const float4*)vp;
      float4 vb = *(const float4*)(vp + 4);
      float vv[8] = {va.x, va.y, va.z, va.w, vb.x, vb.y, vb.z, vb.w};
      #pragma unroll
      for (int e = 0; e < 8; ++e) {
        const int d = d0 + e;
        const int sv = (jr >> 3) ^ ((d >> 1) & 3);
        vt_lds[d * 32 + sv * 8 + (jr & 7)] = f2bf(vv[e]);
      }
    }
    __syncthreads();

    // wave-uniform skip of fully-masked tiles (barrier counts stay matched)
    const bool active = (kj0 <= qw0 + 15) && (kj0 + 31 >= qw0 - la + 1);
    if (active) {
      // ---- S^T[j][q] = K * Q^T : two 16-key subtiles, K=64 in 2 chunks ----
      f4v sacc[2] = {{0.f,0.f,0.f,0.f},{0.f,0.f,0.f,0.f}};
      #pragma unroll
      for (int ch = 0; ch < 2; ++ch) {
        const int slot = ((ch << 2) + g) ^ (c & 7);
        s8v kf0 = *(const s8v*)&k_lds[(c) * 64 + slot * 8];
        s8v kf1 = *(const s8v*)&k_lds[(16 + c) * 64 + slot * 8];
        sacc[0] = __builtin_amdgcn_mfma_f32_16x16x32_bf16(kf0, qf[ch], sacc[0], 0, 0, 0);
        sacc[1] = __builtin_amdgcn_mfma_f32_16x16x32_bf16(kf1, qf[ch], sacc[1], 0, 0, 0);
      }

      // ---- scale + mask + online softmax (lane's full row: 8 vals + 2 shfl) ----
      float p[2][4];
      float tmax = -1e30f;
      #pragma unroll
      for (int sub = 0; sub < 2; ++sub)
        #pragma unroll
        for (int r = 0; r < 4; ++r) {
          const int jt = kj0 + 16 * sub + 4 * g + r;
          float s = sacc[sub][r] * 0.125f;
          s = (jt >= jlo && jt <= i_row) ? s : -1e30f;
          p[sub][r] = s;
          tmax = fmaxf(tmax, s);
        }
      tmax = fmaxf(tmax, __shfl_xor(tmax, 16, 64));
      tmax = fmaxf(tmax, __shfl_xor(tmax, 32, 64));
      const float mnew = fmaxf(m, tmax);
      const float corr = __expf(m - mnew);   // =0 when junk->real transition: wipes junk
      m = mnew;

      float psum = 0.f;
      s4v pb[2];
      #pragma unroll
      for (int sub = 0; sub < 2; ++sub)
        #pragma unroll
        for (int r = 0; r < 4; ++r) {
          const float e = __expf(p[sub][r] - mnew);  // masked: exp(-1e30-m)=0
          psum += e;
          pb[sub][r] = f2bf(e);
        }
      psum += __shfl_xor(psum, 16, 64);
      psum += __shfl_xor(psum, 32, 64);
      lsum = lsum * corr + psum;
      #pragma unroll
      for (int dt = 0; dt < 4; ++dt) {
        acc_o[dt][0] *= corr; acc_o[dt][1] *= corr;
        acc_o[dt][2] *= corr; acc_o[dt][3] *= corr;
      }

      // ---- PV: out^T += V^T * P^T ; 16x16x16 so P layout matches acc (no shuffles) ----
      #pragma unroll
      for (int dt = 0; dt < 4; ++dt) {
        const int d = dt * 16 + c;
        #pragma unroll
        for (int sub = 0; sub < 2; ++sub) {
          const int sv = ((sub << 1) + (g >> 1)) ^ ((c >> 1) & 3);
          s4v vf = *(const s4v*)&vt_lds[d * 32 + sv * 8 + 4 * (g & 1)];
          acc_o[dt] = MFMA16(vf, pb[sub], acc_o[dt]);
        }
      }
    }
  }

  // ---- epilogue: normalize, transpose via LDS, coalesced f32x4 stores ----
  const float inv = 1.f / lsum;   // every row has >=1 valid key -> lsum >= 1
  #pragma unroll
  for (int dt = 0; dt < 4; ++dt)
    #pragma unroll
    for (int r = 0; r < 4; ++r)
      o_lds[w * 16 + c][dt * 16 + 4 * g + r] = acc_o[dt][r] * inv;
  __syncthreads();
  {
    const int row = tid >> 2;
    const int col0 = (tid & 3) << 4;
    const int b = bh / HH;
    const int h = bh % HH;
    float* op = out + ((size_t)b * TT + (q0 + row)) * (HH * DD) + h * DD + col0;
    #pragma unroll
    for (int x = 0; x < 4; ++x)
      *(float4*)(op + 4 * x) = *(const float4*)&o_lds[row][col0 + 4 * x];
  }
}

extern "C" void kernel_launch(void* const* d_in, const int* in_sizes, int n_in,
                              void* d_out, int out_size, void* d_ws, size_t ws_size,
                              hipStream_t stream) {
  const float* q = (const float*)d_in[0];
  const float* k = (const float*)d_in[1];
  const float* v = (const float*)d_in[2];
  const int* la = (const int*)d_in[3];
  float* out = (float*)d_out;
  (void)in_sizes; (void)n_in; (void)out_size; (void)d_ws; (void)ws_size;

  dim3 grid(24 * 64);   // (b,h) major, 64 q-tiles minor
  dim3 block(256);
  lma_attn_kernel<<<grid, block, 0, stream>>>(q, k, v, la, out);
}